// Round 5
// baseline (240.734 us; speedup 1.0000x reference)
//
#include <hip/hip_runtime.h>
#include <math.h>

// Problem constants
static constexpr int kB = 2;
static constexpr int kS = 2048;
static constexpr int kE = 1024;
static constexpr int kH = 16;
static constexpr int kD = 64;
static constexpr int kTRIL = 2080; // 64*65/2

typedef __attribute__((ext_vector_type(8))) __bf16 bf16x8;
typedef __attribute__((ext_vector_type(4))) __bf16 bf16x4;
typedef __attribute__((ext_vector_type(4))) float f32x4;

// Split f32 into bf16 hi (truncation) + bf16 lo (RNE of residual).
__device__ __forceinline__ void split_bf16(float f, __bf16& hi, __bf16& lo) {
    unsigned bits = __builtin_bit_cast(unsigned, f);
    hi = __builtin_bit_cast(__bf16, (unsigned short)(bits >> 16));
    float hf = __builtin_bit_cast(float, bits & 0xFFFF0000u);
    lo = (__bf16)(f - hf);
}

// Async global->LDS 16B copy. LDS dest is wave-uniform (HW adds lane*16).
__device__ __forceinline__ void gload_lds16(const void* g, void* l) {
    __builtin_amdgcn_global_load_lds(
        (const __attribute__((address_space(1))) unsigned int*)g,
        (__attribute__((address_space(3))) unsigned int*)l, 16, 0, 0);
}

// ---------------------------------------------------------------------------
// f32 -> bf16 (RNE), 4 elems/thread (for Wv, Wo).
// ---------------------------------------------------------------------------
__global__ __launch_bounds__(256) void cast_bf16_kernel(
    const float* __restrict__ in, __bf16* __restrict__ out, int n4)
{
    const int i = blockIdx.x * 256 + threadIdx.x;
    if (i >= n4) return;
    const float4 v = ((const float4*)in)[i];
    bf16x4 o = {(__bf16)v.x, (__bf16)v.y, (__bf16)v.z, (__bf16)v.w};
    ((bf16x4*)out)[i] = o;
}

// ---------------------------------------------------------------------------
// Wqk[h] = L_h @ L_h^T from packed lower-triangular params.
// ---------------------------------------------------------------------------
__global__ __launch_bounds__(256) void build_wqk(
    const float* __restrict__ params, float* __restrict__ wqk)
{
    __shared__ float p[kTRIL];
    const int h = blockIdx.x;
    for (int i = threadIdx.x; i < kTRIL; i += 256) p[i] = params[h * kTRIL + i];
    __syncthreads();
    for (int idx = threadIdx.x; idx < kD * kD; idx += 256) {
        const int i = idx >> 6;
        const int j = idx & 63;
        const int m = i < j ? i : j;
        const float* pi = p + (i * (i + 1)) / 2;
        const float* pj = p + (j * (j + 1)) / 2;
        float s = 0.f;
        for (int k = 0; k <= m; ++k) s += pi[k] * pj[k];
        wqk[h * kD * kD + idx] = s;
    }
}

// ---------------------------------------------------------------------------
// Q = (xh @ Wqk) * 0.125 * log2(e), written as split bf16 (Qh, Ql).
// Also emits the hi/lo split of x itself (fused; x row already in LDS).
// ---------------------------------------------------------------------------
__global__ __launch_bounds__(256) void q_proj(
    const float* __restrict__ x, const float* __restrict__ wqk,
    __bf16* __restrict__ Qh, __bf16* __restrict__ Ql,
    __bf16* __restrict__ xhO, __bf16* __restrict__ xlO)
{
    __shared__ float xs[kE];
    const int bs = blockIdx.x;
    const int tid = threadIdx.x;
    const float4 xv4 = ((const float4*)(x + (size_t)bs * kE))[tid];
    ((float4*)xs)[tid] = xv4;
    // fused split of x
    {
        const float f[4] = {xv4.x, xv4.y, xv4.z, xv4.w};
        bf16x4 hv, lv;
#pragma unroll
        for (int j = 0; j < 4; ++j) { __bf16 a, c; split_bf16(f[j], a, c); hv[j] = a; lv[j] = c; }
        ((bf16x4*)(xhO + (size_t)bs * kE))[tid] = hv;
        ((bf16x4*)(xlO + (size_t)bs * kE))[tid] = lv;
    }
    __syncthreads();
    const int o = tid * 4;
    const int h = o >> 6;
    const int e = o & 63;
    const float* W = wqk + h * kD * kD;
    float a0 = 0.f, a1 = 0.f, a2 = 0.f, a3 = 0.f;
    const float* xh = xs + h * kD;
#pragma unroll 8
    for (int d = 0; d < kD; ++d) {
        const float xv = xh[d];
        const float4 w = *(const float4*)(W + d * kD + e);
        a0 += xv * w.x; a1 += xv * w.y; a2 += xv * w.z; a3 += xv * w.w;
    }
    const float sc = 0.125f * 1.44269504088896340736f;
    const float f[4] = {a0 * sc, a1 * sc, a2 * sc, a3 * sc};
    bf16x4 hv, lv;
#pragma unroll
    for (int j = 0; j < 4; ++j) { __bf16 a, b; split_bf16(f[j], a, b); hv[j] = a; lv[j] = b; }
    ((bf16x4*)(Qh + (size_t)bs * kE))[tid] = hv;
    ((bf16x4*)(Ql + (size_t)bs * kE))[tid] = lv;
}

// ---------------------------------------------------------------------------
// Single-pass bf16 MFMA GEMM: C = A @ Bw^T + bias (f32 accumulate).
// 128x128 tile, BK=64, 4 waves (2x2), 2-phase double-buffered global_load_lds.
// LDS rows = 64 bf16 (128B), 8 x 16B chunks, XOR swizzle chunk^(row&7).
// MODE 0: C f32 [M,N].  MODE 1: C bf16 transposed to Vt[b,h,d,s].
// ---------------------------------------------------------------------------
template <int MODE>
__global__ __launch_bounds__(256) void gemm_bf16(
    const __bf16* __restrict__ A, const __bf16* __restrict__ Bw,
    const float* __restrict__ bias, void* __restrict__ Cout,
    int M, int N, int K)
{
    __shared__ __bf16 Ab[2][128 * 64];
    __shared__ __bf16 Bb[2][128 * 64];

    const int tid = threadIdx.x;
    const int w = tid >> 6, l = tid & 63;
    const int g = l >> 4, lm = l & 15;
    const int wm = w >> 1, wn = w & 1;
    const int bm = blockIdx.y * 128, bn = blockIdx.x * 128;
    const int srow = 8 * w + (l >> 3);
    const int cp = l & 7;

    f32x4 acc[4][4];
#pragma unroll
    for (int i = 0; i < 4; ++i)
#pragma unroll
        for (int j = 0; j < 4; ++j) acc[i][j] = (f32x4){0.f, 0.f, 0.f, 0.f};

    auto stage = [&](int buf, int k0) {
#pragma unroll
        for (int j = 0; j < 4; ++j) {
            const int r = 32 * j + srow;
            const int c = cp ^ (r & 7);
            gload_lds16(A + (size_t)(bm + r) * K + k0 + c * 8, &Ab[buf][j * 2048 + w * 512]);
            gload_lds16(Bw + (size_t)(bn + r) * K + k0 + c * 8, &Bb[buf][j * 2048 + w * 512]);
        }
    };

    stage(0, 0);
    __syncthreads();
    int cur = 0;
    const int NT = K / 64;
    for (int t = 0; t < NT; ++t) {
        if (t + 1 < NT) stage(cur ^ 1, 64 * (t + 1));

        bf16x8 a[4][2], bf[4][2];
#pragma unroll
        for (int i = 0; i < 4; ++i) {
            const int rA = wm * 64 + i * 16 + lm;
            const int rB = wn * 64 + i * 16 + lm;
#pragma unroll
            for (int ks = 0; ks < 2; ++ks) {
                a[i][ks]  = *(const bf16x8*)&Ab[cur][rA * 64 + (((4 * ks + g) ^ (rA & 7)) * 8)];
                bf[i][ks] = *(const bf16x8*)&Bb[cur][rB * 64 + (((4 * ks + g) ^ (rB & 7)) * 8)];
            }
        }
#pragma unroll
        for (int ks = 0; ks < 2; ++ks)
#pragma unroll
            for (int mi = 0; mi < 4; ++mi)
#pragma unroll
                for (int ni = 0; ni < 4; ++ni)
                    acc[mi][ni] = __builtin_amdgcn_mfma_f32_16x16x32_bf16(
                        a[mi][ks], bf[ni][ks], acc[mi][ni], 0, 0, 0);

        __syncthreads();
        cur ^= 1;
    }

    if (MODE == 0) {
        float bv4[4];
#pragma unroll
        for (int ni = 0; ni < 4; ++ni) bv4[ni] = bias[bn + wn * 64 + ni * 16 + lm];
        float* C = (float*)Cout;
#pragma unroll
        for (int mi = 0; mi < 4; ++mi) {
            const int row0 = bm + wm * 64 + mi * 16 + g * 4;
#pragma unroll
            for (int r = 0; r < 4; ++r) {
                float* crow = C + (size_t)(row0 + r) * N;
#pragma unroll
                for (int ni = 0; ni < 4; ++ni)
                    crow[bn + wn * 64 + ni * 16 + lm] = acc[mi][ni][r] + bv4[ni];
            }
        }
    } else {
        __bf16* Vt = (__bf16*)Cout;
#pragma unroll
        for (int ni = 0; ni < 4; ++ni) {
            const int col = bn + wn * 64 + ni * 16 + lm;
            const float bb = bias[col];
            const int hh = col >> 6, dd = col & 63;
#pragma unroll
            for (int mi = 0; mi < 4; ++mi) {
                const int tok = bm + wm * 64 + mi * 16 + g * 4;
                const int b = tok >> 11, s0 = tok & 2047;
                bf16x4 pk;
#pragma unroll
                for (int r = 0; r < 4; ++r) pk[r] = (__bf16)(acc[mi][ni][r] + bb);
                *(bf16x4*)(Vt + ((size_t)(b * kH + hh) * kD + dd) * kS + s0) = pk;
            }
        }
    }
}

// ---------------------------------------------------------------------------
// MFMA flash attention (swapped-operand), split-bf16 QK^T, bf16 V^T input.
// 4 waves; BQ=64 (16 q/wave); BK=64.
// Khi + Vt: LDS, double-buffered (one barrier/tile, stage issued pre-compute).
// Klo: streamed global->registers (L1-shared across the 4 waves).
// P: per-wave LDS bounce (no barrier). Defer-max softmax in log2 space.
// ---------------------------------------------------------------------------
__global__ __launch_bounds__(256, 4) void flash_attn_mfma(
    const __bf16* __restrict__ Qh, const __bf16* __restrict__ Ql,
    const __bf16* __restrict__ xh, const __bf16* __restrict__ xl,
    const __bf16* __restrict__ VtG, __bf16* __restrict__ AO)
{
    __shared__ __bf16 Kh[2][64 * 64];
    __shared__ __bf16 Vts[2][64 * 64];
    __shared__ __bf16 Pl[4][16 * 64];

    const int tid = threadIdx.x;
    const int l = tid & 63;
    const int w = tid >> 6;
    const int g = l >> 4;
    const int lm = l & 15;
    const int q0 = blockIdx.x * 64;
    const int h = blockIdx.y;
    const int b = blockIdx.z;

    // Q fragments (hi/lo), persistent.
    bf16x8 qh[2], ql[2];
    {
        const size_t qoff = ((size_t)(b * kS + q0 + w * 16 + lm)) * kE + h * kD + g * 8;
#pragma unroll
        for (int ks = 0; ks < 2; ++ks) {
            qh[ks] = *(const bf16x8*)(Qh + qoff + 32 * ks);
            ql[ks] = *(const bf16x8*)(Ql + qoff + 32 * ks);
        }
    }

    const f32x4 zero4 = {0.f, 0.f, 0.f, 0.f};
    f32x4 oacc[4];
#pragma unroll
    for (int i = 0; i < 4; ++i) oacc[i] = zero4;
    float mrun = -INFINITY, lsum = 0.f;

    const int srow = 8 * w + (l >> 3);
    const int cpos = l & 7;
    const size_t vthead = ((size_t)(b * kH + h) * kD) * kS;
    const size_t xbase = (size_t)(b * kS) * kE + h * kD;

    // hoisted LDS element offsets (shared by Kh, Vts rows d/key=16mt+lm, and Pl row lm)
    const int rowb = lm * 64;
    const int swz0 = ((0 + g) ^ (lm & 7)) * 8;   // ks=0 chunk
    const int swz1 = ((4 + g) ^ (lm & 7)) * 8;   // ks=1 chunk
    int padr[4];
#pragma unroll
    for (int mt = 0; mt < 4; ++mt)
        padr[mt] = rowb + (((2 * mt + (g >> 1)) ^ (lm & 7)) * 8) + (g & 1) * 4;

    auto stage = [&](int buf, int k0) {
#pragma unroll
        for (int j = 0; j < 2; ++j) {
            const int r = 32 * j + srow;
            const int c = cpos ^ (r & 7);
            gload_lds16(xh + xbase + (size_t)(k0 + r) * kE + c * 8,
                        &Kh[buf][j * 2048 + w * 512]);
            gload_lds16(VtG + vthead + (size_t)r * kS + k0 + c * 8,
                        &Vts[buf][j * 2048 + w * 512]);
        }
    };

    stage(0, 0);
    int cur = 0;
    for (int k0 = 0; k0 < kS; k0 += 64) {
        __syncthreads();                      // buf[cur] (tile k0) ready
        if (k0 + 64 < kS) stage(cur ^ 1, k0 + 64);

        // ---- stream K-lo fragments to registers (shared region -> L1) ----
        bf16x8 kl[4][2];
#pragma unroll
        for (int mt = 0; mt < 4; ++mt) {
            const __bf16* p = xl + xbase + (size_t)(k0 + 16 * mt + lm) * kE + 8 * g;
            kl[mt][0] = *(const bf16x8*)p;
            kl[mt][1] = *(const bf16x8*)(p + 32);
        }

        // ---- QK^T swapped: S^T[key=16mt+g*4+jj][q=lm] ----
        f32x4 sacc[4];
#pragma unroll
        for (int i = 0; i < 4; ++i) sacc[i] = zero4;
#pragma unroll
        for (int mt = 0; mt < 4; ++mt) {
            bf16x8 k0f = *(const bf16x8*)&Kh[cur][mt * 1024 + rowb + swz0];
            bf16x8 k1f = *(const bf16x8*)&Kh[cur][mt * 1024 + rowb + swz1];
            sacc[mt] = __builtin_amdgcn_mfma_f32_16x16x32_bf16(k0f, qh[0], sacc[mt], 0, 0, 0);
            sacc[mt] = __builtin_amdgcn_mfma_f32_16x16x32_bf16(k0f, ql[0], sacc[mt], 0, 0, 0);
            sacc[mt] = __builtin_amdgcn_mfma_f32_16x16x32_bf16(k1f, qh[1], sacc[mt], 0, 0, 0);
            sacc[mt] = __builtin_amdgcn_mfma_f32_16x16x32_bf16(k1f, ql[1], sacc[mt], 0, 0, 0);
        }
#pragma unroll
        for (int mt = 0; mt < 4; ++mt) {
            sacc[mt] = __builtin_amdgcn_mfma_f32_16x16x32_bf16(kl[mt][0], qh[0], sacc[mt], 0, 0, 0);
            sacc[mt] = __builtin_amdgcn_mfma_f32_16x16x32_bf16(kl[mt][1], qh[1], sacc[mt], 0, 0, 0);
        }

        // ---- online softmax with defer-max (log2 space) ----
        float tmax = -INFINITY;
#pragma unroll
        for (int mt = 0; mt < 4; ++mt)
#pragma unroll
            for (int jj = 0; jj < 4; ++jj) tmax = fmaxf(tmax, sacc[mt][jj]);
        tmax = fmaxf(tmax, __shfl_xor(tmax, 16));
        tmax = fmaxf(tmax, __shfl_xor(tmax, 32));
        if (__any(tmax > mrun + 8.0f)) {
            const float mnew = fmaxf(mrun, tmax);
            const float alpha = exp2f(mrun - mnew);
            lsum *= alpha;
#pragma unroll
            for (int i = 0; i < 4; ++i) oacc[i] *= alpha;
            mrun = mnew;
        }
        float tsum = 0.f;
#pragma unroll
        for (int mt = 0; mt < 4; ++mt) {
            bf16x4 pv;
#pragma unroll
            for (int jj = 0; jj < 4; ++jj) {
                const float p = exp2f(sacc[mt][jj] - mrun);
                tsum += p;
                pv[jj] = (__bf16)p;
            }
            *(bf16x4*)&Pl[w][padr[mt]] = pv;
        }
        tsum += __shfl_xor(tsum, 16);
        tsum += __shfl_xor(tsum, 32);
        lsum += tsum;

        // ---- PV: O^T[d][q] += Vt . P^T (pf hoisted; per-wave, no barrier) ----
        bf16x8 pf0 = *(const bf16x8*)&Pl[w][rowb + swz0];
        bf16x8 pf1 = *(const bf16x8*)&Pl[w][rowb + swz1];
#pragma unroll
        for (int mt = 0; mt < 4; ++mt) {
            bf16x8 v0 = *(const bf16x8*)&Vts[cur][mt * 1024 + rowb + swz0];
            bf16x8 v1 = *(const bf16x8*)&Vts[cur][mt * 1024 + rowb + swz1];
            oacc[mt] = __builtin_amdgcn_mfma_f32_16x16x32_bf16(v0, pf0, oacc[mt], 0, 0, 0);
            oacc[mt] = __builtin_amdgcn_mfma_f32_16x16x32_bf16(v1, pf1, oacc[mt], 0, 0, 0);
        }
        cur ^= 1;
    }

    const float inv = 1.0f / lsum;
    const size_t obase = ((size_t)(b * kS + q0 + w * 16 + lm)) * kE + h * kD;
#pragma unroll
    for (int mt = 0; mt < 4; ++mt) {
        bf16x4 pk;
#pragma unroll
        for (int jj = 0; jj < 4; ++jj) pk[jj] = (__bf16)(oacc[mt][jj] * inv);
        *(bf16x4*)(AO + obase + 16 * mt + 4 * g) = pk;
    }
}

// ---------------------------------------------------------------------------
extern "C" void kernel_launch(void* const* d_in, const int* in_sizes, int n_in,
                              void* d_out, int out_size, void* d_ws, size_t ws_size,
                              hipStream_t stream) {
    (void)in_sizes; (void)n_in; (void)out_size; (void)ws_size;
    const float* x      = (const float*)d_in[0];
    const float* params = (const float*)d_in[1];
    const float* Wv     = (const float*)d_in[2];
    const float* bv     = (const float*)d_in[3];
    const float* Wo     = (const float*)d_in[4];
    const float* bo     = (const float*)d_in[5];
    float* out = (float*)d_out;

    const size_t NE = (size_t)kB * kS * kE;   // 4194304
    const size_t NW = (size_t)kE * kE;        // 1048576

    char* ws = (char*)d_ws;
    size_t off = 0;
    float*  wqk = (float*)(ws + off);  off += (size_t)kH * kD * kD * 4;  // 256KB
    __bf16* xh  = (__bf16*)(ws + off); off += NE * 2;
    __bf16* xl  = (__bf16*)(ws + off); off += NE * 2;
    __bf16* wvb = (__bf16*)(ws + off); off += NW * 2;
    __bf16* wob = (__bf16*)(ws + off); off += NW * 2;
    __bf16* Qh  = (__bf16*)(ws + off); off += NE * 2;
    __bf16* Ql  = (__bf16*)(ws + off); off += NE * 2;
    __bf16* VtG = (__bf16*)(ws + off); off += NE * 2;
    __bf16* AO  = (__bf16*)(ws + off); off += NE * 2;

    cast_bf16_kernel<<<(int)(NW / 4 / 256), 256, 0, stream>>>(Wv, wvb, (int)(NW / 4));
    cast_bf16_kernel<<<(int)(NW / 4 / 256), 256, 0, stream>>>(Wo, wob, (int)(NW / 4));
    build_wqk<<<kH, 256, 0, stream>>>(params, wqk);
    q_proj<<<kB * kS, 256, 0, stream>>>(x, wqk, Qh, Ql, xh, xl);
    gemm_bf16<1><<<dim3(kE / 128, (kB * kS) / 128), 256, 0, stream>>>(
        xh, wvb, bv, (void*)VtG, kB * kS, kE, kE);
    flash_attn_mfma<<<dim3(kS / 64, kH, kB), 256, 0, stream>>>(Qh, Ql, xh, xl, VtG, AO);
    gemm_bf16<0><<<dim3(kE / 128, (kB * kS) / 128), 256, 0, stream>>>(
        AO, wob, bo, (void*)out, kB * kS, kE, kE);
}

// Round 6
// 195.307 us; speedup vs baseline: 1.2326x; 1.2326x over previous
//
#include <hip/hip_runtime.h>
#include <math.h>

// Problem constants
static constexpr int kB = 2;
static constexpr int kS = 2048;
static constexpr int kE = 1024;
static constexpr int kH = 16;
static constexpr int kD = 64;
static constexpr int kTRIL = 2080; // 64*65/2

typedef __attribute__((ext_vector_type(8))) __bf16 bf16x8;
typedef __attribute__((ext_vector_type(4))) __bf16 bf16x4;
typedef __attribute__((ext_vector_type(4))) float f32x4;
typedef __attribute__((ext_vector_type(16))) float f32x16;
typedef __attribute__((ext_vector_type(4))) unsigned int u32x4;

// Split f32 into bf16 hi (truncation) + bf16 lo (RNE of residual).
__device__ __forceinline__ void split_bf16(float f, __bf16& hi, __bf16& lo) {
    unsigned bits = __builtin_bit_cast(unsigned, f);
    hi = __builtin_bit_cast(__bf16, (unsigned short)(bits >> 16));
    float hf = __builtin_bit_cast(float, bits & 0xFFFF0000u);
    lo = (__bf16)(f - hf);
}

// Async global->LDS 16B copy. LDS dest is wave-uniform (HW adds lane*16).
__device__ __forceinline__ void gload_lds16(const void* g, void* l) {
    __builtin_amdgcn_global_load_lds(
        (const __attribute__((address_space(1))) unsigned int*)g,
        (__attribute__((address_space(3))) unsigned int*)l, 16, 0, 0);
}

__device__ __forceinline__ unsigned pack_bf16(float a, float b) {
    unsigned ha = (unsigned)__builtin_bit_cast(unsigned short, (__bf16)a);
    unsigned hb = (unsigned)__builtin_bit_cast(unsigned short, (__bf16)b);
    return ha | (hb << 16);
}

// ---------------------------------------------------------------------------
// f32 -> bf16 (RNE), 4 elems/thread (for Wv, Wo).
// ---------------------------------------------------------------------------
__global__ __launch_bounds__(256) void cast_bf16_kernel(
    const float* __restrict__ in, __bf16* __restrict__ out, int n4)
{
    const int i = blockIdx.x * 256 + threadIdx.x;
    if (i >= n4) return;
    const float4 v = ((const float4*)in)[i];
    bf16x4 o = {(__bf16)v.x, (__bf16)v.y, (__bf16)v.z, (__bf16)v.w};
    ((bf16x4*)out)[i] = o;
}

// ---------------------------------------------------------------------------
// Wqk[h] = L_h @ L_h^T from packed lower-triangular params.
// ---------------------------------------------------------------------------
__global__ __launch_bounds__(256) void build_wqk(
    const float* __restrict__ params, float* __restrict__ wqk)
{
    __shared__ float p[kTRIL];
    const int h = blockIdx.x;
    for (int i = threadIdx.x; i < kTRIL; i += 256) p[i] = params[h * kTRIL + i];
    __syncthreads();
    for (int idx = threadIdx.x; idx < kD * kD; idx += 256) {
        const int i = idx >> 6;
        const int j = idx & 63;
        const int m = i < j ? i : j;
        const float* pi = p + (i * (i + 1)) / 2;
        const float* pj = p + (j * (j + 1)) / 2;
        float s = 0.f;
        for (int k = 0; k <= m; ++k) s += pi[k] * pj[k];
        wqk[h * kD * kD + idx] = s;
    }
}

// ---------------------------------------------------------------------------
// Q = (xh @ Wqk) * 0.125 * log2(e), written as split bf16 (Qh, Ql).
// Also emits the hi/lo split of x itself (fused; x row already in regs).
// ---------------------------------------------------------------------------
__global__ __launch_bounds__(256) void q_proj(
    const float* __restrict__ x, const float* __restrict__ wqk,
    __bf16* __restrict__ Qh, __bf16* __restrict__ Ql,
    __bf16* __restrict__ xhO, __bf16* __restrict__ xlO)
{
    __shared__ float xs[kE];
    const int bs = blockIdx.x;
    const int tid = threadIdx.x;
    const float4 xv4 = ((const float4*)(x + (size_t)bs * kE))[tid];
    ((float4*)xs)[tid] = xv4;
    {
        const float f[4] = {xv4.x, xv4.y, xv4.z, xv4.w};
        bf16x4 hv, lv;
#pragma unroll
        for (int j = 0; j < 4; ++j) { __bf16 a, c; split_bf16(f[j], a, c); hv[j] = a; lv[j] = c; }
        ((bf16x4*)(xhO + (size_t)bs * kE))[tid] = hv;
        ((bf16x4*)(xlO + (size_t)bs * kE))[tid] = lv;
    }
    __syncthreads();
    const int o = tid * 4;
    const int h = o >> 6;
    const int e = o & 63;
    const float* W = wqk + h * kD * kD;
    float a0 = 0.f, a1 = 0.f, a2 = 0.f, a3 = 0.f;
    const float* xh = xs + h * kD;
#pragma unroll 8
    for (int d = 0; d < kD; ++d) {
        const float xv = xh[d];
        const float4 w = *(const float4*)(W + d * kD + e);
        a0 += xv * w.x; a1 += xv * w.y; a2 += xv * w.z; a3 += xv * w.w;
    }
    const float sc = 0.125f * 1.44269504088896340736f;
    const float f[4] = {a0 * sc, a1 * sc, a2 * sc, a3 * sc};
    bf16x4 hv, lv;
#pragma unroll
    for (int j = 0; j < 4; ++j) { __bf16 a, b; split_bf16(f[j], a, b); hv[j] = a; lv[j] = b; }
    ((bf16x4*)(Qh + (size_t)bs * kE))[tid] = hv;
    ((bf16x4*)(Ql + (size_t)bs * kE))[tid] = lv;
}

// ---------------------------------------------------------------------------
// Single-pass bf16 MFMA GEMM: C = A @ Bw^T + bias (f32 accumulate).
// 128x128 tile, BK=64, 4 waves (2x2), 2-phase double-buffered global_load_lds.
// MODE 0: C f32 [M,N].  MODE 1: C bf16 transposed to Vt[b,h,d,s].
// ---------------------------------------------------------------------------
template <int MODE>
__global__ __launch_bounds__(256) void gemm_bf16(
    const __bf16* __restrict__ A, const __bf16* __restrict__ Bw,
    const float* __restrict__ bias, void* __restrict__ Cout,
    int M, int N, int K)
{
    __shared__ __bf16 Ab[2][128 * 64];
    __shared__ __bf16 Bb[2][128 * 64];

    const int tid = threadIdx.x;
    const int w = tid >> 6, l = tid & 63;
    const int g = l >> 4, lm = l & 15;
    const int wm = w >> 1, wn = w & 1;
    const int bm = blockIdx.y * 128, bn = blockIdx.x * 128;
    const int srow = 8 * w + (l >> 3);
    const int cp = l & 7;

    f32x4 acc[4][4];
#pragma unroll
    for (int i = 0; i < 4; ++i)
#pragma unroll
        for (int j = 0; j < 4; ++j) acc[i][j] = (f32x4){0.f, 0.f, 0.f, 0.f};

    auto stage = [&](int buf, int k0) {
#pragma unroll
        for (int j = 0; j < 4; ++j) {
            const int r = 32 * j + srow;
            const int c = cp ^ (r & 7);
            gload_lds16(A + (size_t)(bm + r) * K + k0 + c * 8, &Ab[buf][j * 2048 + w * 512]);
            gload_lds16(Bw + (size_t)(bn + r) * K + k0 + c * 8, &Bb[buf][j * 2048 + w * 512]);
        }
    };

    stage(0, 0);
    __syncthreads();
    int cur = 0;
    const int NT = K / 64;
    for (int t = 0; t < NT; ++t) {
        if (t + 1 < NT) stage(cur ^ 1, 64 * (t + 1));

        bf16x8 a[4][2], bf[4][2];
#pragma unroll
        for (int i = 0; i < 4; ++i) {
            const int rA = wm * 64 + i * 16 + lm;
            const int rB = wn * 64 + i * 16 + lm;
#pragma unroll
            for (int ks = 0; ks < 2; ++ks) {
                a[i][ks]  = *(const bf16x8*)&Ab[cur][rA * 64 + (((4 * ks + g) ^ (rA & 7)) * 8)];
                bf[i][ks] = *(const bf16x8*)&Bb[cur][rB * 64 + (((4 * ks + g) ^ (rB & 7)) * 8)];
            }
        }
#pragma unroll
        for (int ks = 0; ks < 2; ++ks)
#pragma unroll
            for (int mi = 0; mi < 4; ++mi)
#pragma unroll
                for (int ni = 0; ni < 4; ++ni)
                    acc[mi][ni] = __builtin_amdgcn_mfma_f32_16x16x32_bf16(
                        a[mi][ks], bf[ni][ks], acc[mi][ni], 0, 0, 0);

        __syncthreads();
        cur ^= 1;
    }

    if (MODE == 0) {
        float bv4[4];
#pragma unroll
        for (int ni = 0; ni < 4; ++ni) bv4[ni] = bias[bn + wn * 64 + ni * 16 + lm];
        float* C = (float*)Cout;
#pragma unroll
        for (int mi = 0; mi < 4; ++mi) {
            const int row0 = bm + wm * 64 + mi * 16 + g * 4;
#pragma unroll
            for (int r = 0; r < 4; ++r) {
                float* crow = C + (size_t)(row0 + r) * N;
#pragma unroll
                for (int ni = 0; ni < 4; ++ni)
                    crow[bn + wn * 64 + ni * 16 + lm] = acc[mi][ni][r] + bv4[ni];
            }
        }
    } else {
        __bf16* Vt = (__bf16*)Cout;
#pragma unroll
        for (int ni = 0; ni < 4; ++ni) {
            const int col = bn + wn * 64 + ni * 16 + lm;
            const float bb = bias[col];
            const int hh = col >> 6, dd = col & 63;
#pragma unroll
            for (int mi = 0; mi < 4; ++mi) {
                const int tok = bm + wm * 64 + mi * 16 + g * 4;
                const int b = tok >> 11, s0 = tok & 2047;
                bf16x4 pk;
#pragma unroll
                for (int r = 0; r < 4; ++r) pk[r] = (__bf16)(acc[mi][ni][r] + bb);
                *(bf16x4*)(Vt + ((size_t)(b * kH + hh) * kD + dd) * kS + s0) = pk;
            }
        }
    }
}

// ---------------------------------------------------------------------------
// MFMA flash attention, 32x32x16 shape. BQ=128, 4 waves (32 q each), BK=64.
// S^T = mfma(K, Q): C col = q (lane&31), rows = keys; one q per lane pair.
// K hi/lo + Vt in LDS, double-buffered, ONE barrier per tile.
// P never touches LDS: packed bf16 words + shfl_xor(32) partner exchange
// builds the PV B-fragment in registers. Defer-max softmax, log2 space.
// ---------------------------------------------------------------------------
__global__ __launch_bounds__(256, 2) void flash_attn_mfma(
    const __bf16* __restrict__ Qh, const __bf16* __restrict__ Ql,
    const __bf16* __restrict__ xh, const __bf16* __restrict__ xl,
    const __bf16* __restrict__ VtG, __bf16* __restrict__ AO)
{
    __shared__ __bf16 Kh[2][64 * 64];
    __shared__ __bf16 Kl[2][64 * 64];
    __shared__ __bf16 Vts[2][64 * 64];

    const int tid = threadIdx.x;
    const int l = tid & 63;
    const int w = tid >> 6;
    const int hi = l >> 5;       // lane half (k-block of A/B frags)
    const int lq = l & 31;       // this lane's q column / tile row
    const int q0 = blockIdx.x * 128;
    const int h = blockIdx.y;
    const int b = blockIdx.z;

    // Q B-frags: q = q0+32w+lq, d = 16*ks + 8*hi + j
    bf16x8 qh[4], ql[4];
    {
        const size_t qoff = ((size_t)(b * kS + q0 + 32 * w + lq)) * kE + h * kD + 8 * hi;
#pragma unroll
        for (int ks = 0; ks < 4; ++ks) {
            qh[ks] = *(const bf16x8*)(Qh + qoff + 16 * ks);
            ql[ks] = *(const bf16x8*)(Ql + qoff + 16 * ks);
        }
    }

    f32x16 oacc[2];
#pragma unroll
    for (int dt = 0; dt < 2; ++dt)
#pragma unroll
        for (int r = 0; r < 16; ++r) oacc[dt][r] = 0.f;
    float mrun = -INFINITY, lsum = 0.f;   // lsum: per-lane partial (reduced at end)

    const int srow = 8 * w + (l >> 3);
    const int cpos = l & 7;
    const size_t vthead = ((size_t)(b * kH + h) * kD) * kS;
    const size_t xbase = (size_t)(b * kS) * kE + h * kD;

    auto stage = [&](int buf, int k0) {
#pragma unroll
        for (int j = 0; j < 2; ++j) {
            const int r = 32 * j + srow;
            const int c = cpos ^ (r & 7);
            gload_lds16(xh + xbase + (size_t)(k0 + r) * kE + c * 8, &Kh[buf][j * 2048 + w * 512]);
            gload_lds16(xl + xbase + (size_t)(k0 + r) * kE + c * 8, &Kl[buf][j * 2048 + w * 512]);
            gload_lds16(VtG + vthead + (size_t)r * kS + k0 + c * 8, &Vts[buf][j * 2048 + w * 512]);
        }
    };

    stage(0, 0);
    int cur = 0;
    for (int k0 = 0; k0 < kS; k0 += 64) {
        __syncthreads();                      // buf[cur] staged; all waves done with buf[cur^1]
        if (k0 + 64 < kS) stage(cur ^ 1, k0 + 64);

        // ---- QK^T: S^T[key][q], 2 key-tiles of 32, 4 d-steps of 16, 3 passes ----
        f32x16 sacc[2];
#pragma unroll
        for (int kt = 0; kt < 2; ++kt)
#pragma unroll
            for (int r = 0; r < 16; ++r) sacc[kt][r] = 0.f;
#pragma unroll
        for (int kt = 0; kt < 2; ++kt) {
            const int key = 32 * kt + lq;
            const int kr = key * 64;
            const int ksw = key & 7;
#pragma unroll
            for (int ks = 0; ks < 4; ++ks) {
                const int cd = 2 * ks + hi;
                bf16x8 khf = *(const bf16x8*)&Kh[cur][kr + ((cd ^ ksw) * 8)];
                bf16x8 klf = *(const bf16x8*)&Kl[cur][kr + ((cd ^ ksw) * 8)];
                sacc[kt] = __builtin_amdgcn_mfma_f32_32x32x16_bf16(khf, qh[ks], sacc[kt], 0, 0, 0);
                sacc[kt] = __builtin_amdgcn_mfma_f32_32x32x16_bf16(khf, ql[ks], sacc[kt], 0, 0, 0);
                sacc[kt] = __builtin_amdgcn_mfma_f32_32x32x16_bf16(klf, qh[ks], sacc[kt], 0, 0, 0);
            }
        }

        // ---- online softmax with defer-max (log2 space) ----
        float tmax = -INFINITY;
#pragma unroll
        for (int kt = 0; kt < 2; ++kt)
#pragma unroll
            for (int r = 0; r < 16; ++r) tmax = fmaxf(tmax, sacc[kt][r]);
        tmax = fmaxf(tmax, __shfl_xor(tmax, 32));
        if (__any(tmax > mrun + 8.0f)) {
            const float mnew = fmaxf(mrun, tmax);
            const float alpha = exp2f(mrun - mnew);
            lsum *= alpha;
#pragma unroll
            for (int dt = 0; dt < 2; ++dt)
#pragma unroll
                for (int r = 0; r < 16; ++r) oacc[dt][r] *= alpha;
            mrun = mnew;
        }

        // ---- P in registers + PV ----
        // reg r of sacc[kt] holds key_local = (r&3) + 8*(r>>2) + 4*hi (+32*kt).
#pragma unroll
        for (int kt = 0; kt < 2; ++kt) {
            unsigned wds[8], pw[8];
#pragma unroll
            for (int i = 0; i < 8; ++i) {
                const float p0 = exp2f(sacc[kt][2 * i] - mrun);
                const float p1 = exp2f(sacc[kt][2 * i + 1] - mrun);
                lsum += p0 + p1;
                wds[i] = pack_bf16(p0, p1);
            }
#pragma unroll
            for (int i = 0; i < 8; ++i) pw[i] = __shfl_xor(wds[i], 32);
            // B-frag (16 keys x 32 q) for k-steps 2kt and 2kt+1:
            u32x4 f0 = hi ? (u32x4){pw[2], pw[3], wds[2], wds[3]}
                          : (u32x4){wds[0], wds[1], pw[0], pw[1]};
            u32x4 f1 = hi ? (u32x4){pw[6], pw[7], wds[6], wds[7]}
                          : (u32x4){wds[4], wds[5], pw[4], pw[5]};
            bf16x8 pf0 = __builtin_bit_cast(bf16x8, f0);
            bf16x8 pf1 = __builtin_bit_cast(bf16x8, f1);
#pragma unroll
            for (int dt = 0; dt < 2; ++dt) {
                const int d = 32 * dt + lq;
                const int dr = d * 64;
                const int dsw = d & 7;
                bf16x8 v0 = *(const bf16x8*)&Vts[cur][dr + (((4 * kt + hi) ^ dsw) * 8)];
                bf16x8 v1 = *(const bf16x8*)&Vts[cur][dr + (((4 * kt + 2 + hi) ^ dsw) * 8)];
                oacc[dt] = __builtin_amdgcn_mfma_f32_32x32x16_bf16(v0, pf0, oacc[dt], 0, 0, 0);
                oacc[dt] = __builtin_amdgcn_mfma_f32_32x32x16_bf16(v1, pf1, oacc[dt], 0, 0, 0);
            }
        }
        cur ^= 1;
    }

    lsum += __shfl_xor(lsum, 32);
    const float inv = 1.0f / lsum;
    const size_t obase = ((size_t)(b * kS + q0 + 32 * w + lq)) * kE + h * kD;
#pragma unroll
    for (int dt = 0; dt < 2; ++dt)
#pragma unroll
        for (int rr = 0; rr < 4; ++rr) {
            const int d0 = 32 * dt + 8 * rr + 4 * hi;
            bf16x4 pk;
#pragma unroll
            for (int j = 0; j < 4; ++j) pk[j] = (__bf16)(oacc[dt][4 * rr + j] * inv);
            *(bf16x4*)(AO + obase + d0) = pk;
        }
}

// ---------------------------------------------------------------------------
extern "C" void kernel_launch(void* const* d_in, const int* in_sizes, int n_in,
                              void* d_out, int out_size, void* d_ws, size_t ws_size,
                              hipStream_t stream) {
    (void)in_sizes; (void)n_in; (void)out_size; (void)ws_size;
    const float* x      = (const float*)d_in[0];
    const float* params = (const float*)d_in[1];
    const float* Wv     = (const float*)d_in[2];
    const float* bv     = (const float*)d_in[3];
    const float* Wo     = (const float*)d_in[4];
    const float* bo     = (const float*)d_in[5];
    float* out = (float*)d_out;

    const size_t NE = (size_t)kB * kS * kE;   // 4194304
    const size_t NW = (size_t)kE * kE;        // 1048576

    char* ws = (char*)d_ws;
    size_t off = 0;
    float*  wqk = (float*)(ws + off);  off += (size_t)kH * kD * kD * 4;
    __bf16* xh  = (__bf16*)(ws + off); off += NE * 2;
    __bf16* xl  = (__bf16*)(ws + off); off += NE * 2;
    __bf16* wvb = (__bf16*)(ws + off); off += NW * 2;
    __bf16* wob = (__bf16*)(ws + off); off += NW * 2;
    __bf16* Qh  = (__bf16*)(ws + off); off += NE * 2;
    __bf16* Ql  = (__bf16*)(ws + off); off += NE * 2;
    __bf16* VtG = (__bf16*)(ws + off); off += NE * 2;
    __bf16* AO  = (__bf16*)(ws + off); off += NE * 2;

    cast_bf16_kernel<<<(int)(NW / 4 / 256), 256, 0, stream>>>(Wv, wvb, (int)(NW / 4));
    cast_bf16_kernel<<<(int)(NW / 4 / 256), 256, 0, stream>>>(Wo, wob, (int)(NW / 4));
    build_wqk<<<kH, 256, 0, stream>>>(params, wqk);
    q_proj<<<kB * kS, 256, 0, stream>>>(x, wqk, Qh, Ql, xh, xl);
    gemm_bf16<1><<<dim3(kE / 128, (kB * kS) / 128), 256, 0, stream>>>(
        xh, wvb, bv, (void*)VtG, kB * kS, kE, kE);
    flash_attn_mfma<<<dim3(kS / 128, kH, kB), 256, 0, stream>>>(Qh, Ql, xh, xl, VtG, AO);
    gemm_bf16<0><<<dim3(kE / 128, (kB * kS) / 128), 256, 0, stream>>>(
        AO, wob, bo, (void*)out, kB * kS, kE, kE);
}

// Round 8
// 194.955 us; speedup vs baseline: 1.2348x; 1.0018x over previous
//
#include <hip/hip_runtime.h>
#include <math.h>

// Problem constants
static constexpr int kB = 2;
static constexpr int kS = 2048;
static constexpr int kE = 1024;
static constexpr int kH = 16;
static constexpr int kD = 64;
static constexpr int kTRIL = 2080; // 64*65/2

typedef __attribute__((ext_vector_type(8))) __bf16 bf16x8;
typedef __attribute__((ext_vector_type(4))) __bf16 bf16x4;
typedef __attribute__((ext_vector_type(4))) float f32x4;
typedef __attribute__((ext_vector_type(16))) float f32x16;
typedef __attribute__((ext_vector_type(4))) unsigned int u32x4;

// Split f32 into bf16 hi (truncation) + bf16 lo (RNE of residual).
__device__ __forceinline__ void split_bf16(float f, __bf16& hi, __bf16& lo) {
    unsigned bits = __builtin_bit_cast(unsigned, f);
    hi = __builtin_bit_cast(__bf16, (unsigned short)(bits >> 16));
    float hf = __builtin_bit_cast(float, bits & 0xFFFF0000u);
    lo = (__bf16)(f - hf);
}

// Async global->LDS 16B copy. LDS dest is wave-uniform (HW adds lane*16).
__device__ __forceinline__ void gload_lds16(const void* g, void* l) {
    __builtin_amdgcn_global_load_lds(
        (const __attribute__((address_space(1))) unsigned int*)g,
        (__attribute__((address_space(3))) unsigned int*)l, 16, 0, 0);
}

__device__ __forceinline__ unsigned pack_bf16(float a, float b) {
    unsigned ha = (unsigned)__builtin_bit_cast(unsigned short, (__bf16)a);
    unsigned hb = (unsigned)__builtin_bit_cast(unsigned short, (__bf16)b);
    return ha | (hb << 16);
}

// ---------------------------------------------------------------------------
// f32 -> bf16 (RNE), 4 elems/thread (for Wv, Wo).
// ---------------------------------------------------------------------------
__global__ __launch_bounds__(256) void cast_bf16_kernel(
    const float* __restrict__ in, __bf16* __restrict__ out, int n4)
{
    const int i = blockIdx.x * 256 + threadIdx.x;
    if (i >= n4) return;
    const float4 v = ((const float4*)in)[i];
    bf16x4 o = {(__bf16)v.x, (__bf16)v.y, (__bf16)v.z, (__bf16)v.w};
    ((bf16x4*)out)[i] = o;
}

// ---------------------------------------------------------------------------
// Wqk[h] = L_h @ L_h^T from packed lower-triangular params.
// ---------------------------------------------------------------------------
__global__ __launch_bounds__(256) void build_wqk(
    const float* __restrict__ params, float* __restrict__ wqk)
{
    __shared__ float p[kTRIL];
    const int h = blockIdx.x;
    for (int i = threadIdx.x; i < kTRIL; i += 256) p[i] = params[h * kTRIL + i];
    __syncthreads();
    for (int idx = threadIdx.x; idx < kD * kD; idx += 256) {
        const int i = idx >> 6;
        const int j = idx & 63;
        const int m = i < j ? i : j;
        const float* pi = p + (i * (i + 1)) / 2;
        const float* pj = p + (j * (j + 1)) / 2;
        float s = 0.f;
        for (int k = 0; k <= m; ++k) s += pi[k] * pj[k];
        wqk[h * kD * kD + idx] = s;
    }
}

// ---------------------------------------------------------------------------
// Q = (xh @ Wqk) * 0.125 * log2(e), written as split bf16 (Qh, Ql).
// Also emits the hi/lo split of x itself (fused).
// ---------------------------------------------------------------------------
__global__ __launch_bounds__(256) void q_proj(
    const float* __restrict__ x, const float* __restrict__ wqk,
    __bf16* __restrict__ Qh, __bf16* __restrict__ Ql,
    __bf16* __restrict__ xhO, __bf16* __restrict__ xlO)
{
    __shared__ float xs[kE];
    const int bs = blockIdx.x;
    const int tid = threadIdx.x;
    const float4 xv4 = ((const float4*)(x + (size_t)bs * kE))[tid];
    ((float4*)xs)[tid] = xv4;
    {
        const float f[4] = {xv4.x, xv4.y, xv4.z, xv4.w};
        bf16x4 hv, lv;
#pragma unroll
        for (int j = 0; j < 4; ++j) { __bf16 a, c; split_bf16(f[j], a, c); hv[j] = a; lv[j] = c; }
        ((bf16x4*)(xhO + (size_t)bs * kE))[tid] = hv;
        ((bf16x4*)(xlO + (size_t)bs * kE))[tid] = lv;
    }
    __syncthreads();
    const int o = tid * 4;
    const int h = o >> 6;
    const int e = o & 63;
    const float* W = wqk + h * kD * kD;
    float a0 = 0.f, a1 = 0.f, a2 = 0.f, a3 = 0.f;
    const float* xh = xs + h * kD;
#pragma unroll 8
    for (int d = 0; d < kD; ++d) {
        const float xv = xh[d];
        const float4 w = *(const float4*)(W + d * kD + e);
        a0 += xv * w.x; a1 += xv * w.y; a2 += xv * w.z; a3 += xv * w.w;
    }
    const float sc = 0.125f * 1.44269504088896340736f;
    const float f[4] = {a0 * sc, a1 * sc, a2 * sc, a3 * sc};
    bf16x4 hv, lv;
#pragma unroll
    for (int j = 0; j < 4; ++j) { __bf16 a, b; split_bf16(f[j], a, b); hv[j] = a; lv[j] = b; }
    ((bf16x4*)(Qh + (size_t)bs * kE))[tid] = hv;
    ((bf16x4*)(Ql + (size_t)bs * kE))[tid] = lv;
}

// ---------------------------------------------------------------------------
// Single-pass bf16 MFMA GEMM: C = A @ Bw^T + bias (f32 accumulate).
// 128x128 tile, BK=64, 4 waves (2x2), 2-phase double-buffered global_load_lds.
// MODE 0: C f32 [M,N].  MODE 1: C bf16 transposed to Vt[b,h,d,s].
// ---------------------------------------------------------------------------
template <int MODE>
__global__ __launch_bounds__(256) void gemm_bf16(
    const __bf16* __restrict__ A, const __bf16* __restrict__ Bw,
    const float* __restrict__ bias, void* __restrict__ Cout,
    int M, int N, int K)
{
    __shared__ __bf16 Ab[2][128 * 64];
    __shared__ __bf16 Bb[2][128 * 64];

    const int tid = threadIdx.x;
    const int w = tid >> 6, l = tid & 63;
    const int g = l >> 4, lm = l & 15;
    const int wm = w >> 1, wn = w & 1;
    const int bm = blockIdx.y * 128, bn = blockIdx.x * 128;
    const int srow = 8 * w + (l >> 3);
    const int cp = l & 7;

    f32x4 acc[4][4];
#pragma unroll
    for (int i = 0; i < 4; ++i)
#pragma unroll
        for (int j = 0; j < 4; ++j) acc[i][j] = (f32x4){0.f, 0.f, 0.f, 0.f};

    auto stage = [&](int buf, int k0) {
#pragma unroll
        for (int j = 0; j < 4; ++j) {
            const int r = 32 * j + srow;
            const int c = cp ^ (r & 7);
            gload_lds16(A + (size_t)(bm + r) * K + k0 + c * 8, &Ab[buf][j * 2048 + w * 512]);
            gload_lds16(Bw + (size_t)(bn + r) * K + k0 + c * 8, &Bb[buf][j * 2048 + w * 512]);
        }
    };

    stage(0, 0);
    __syncthreads();
    int cur = 0;
    const int NT = K / 64;
    for (int t = 0; t < NT; ++t) {
        if (t + 1 < NT) stage(cur ^ 1, 64 * (t + 1));

        bf16x8 a[4][2], bf[4][2];
#pragma unroll
        for (int i = 0; i < 4; ++i) {
            const int rA = wm * 64 + i * 16 + lm;
            const int rB = wn * 64 + i * 16 + lm;
#pragma unroll
            for (int ks = 0; ks < 2; ++ks) {
                a[i][ks]  = *(const bf16x8*)&Ab[cur][rA * 64 + (((4 * ks + g) ^ (rA & 7)) * 8)];
                bf[i][ks] = *(const bf16x8*)&Bb[cur][rB * 64 + (((4 * ks + g) ^ (rB & 7)) * 8)];
            }
        }
#pragma unroll
        for (int ks = 0; ks < 2; ++ks)
#pragma unroll
            for (int mi = 0; mi < 4; ++mi)
#pragma unroll
                for (int ni = 0; ni < 4; ++ni)
                    acc[mi][ni] = __builtin_amdgcn_mfma_f32_16x16x32_bf16(
                        a[mi][ks], bf[ni][ks], acc[mi][ni], 0, 0, 0);

        __syncthreads();
        cur ^= 1;
    }

    if (MODE == 0) {
        float bv4[4];
#pragma unroll
        for (int ni = 0; ni < 4; ++ni) bv4[ni] = bias[bn + wn * 64 + ni * 16 + lm];
        float* C = (float*)Cout;
#pragma unroll
        for (int mi = 0; mi < 4; ++mi) {
            const int row0 = bm + wm * 64 + mi * 16 + g * 4;
#pragma unroll
            for (int r = 0; r < 4; ++r) {
                float* crow = C + (size_t)(row0 + r) * N;
#pragma unroll
                for (int ni = 0; ni < 4; ++ni)
                    crow[bn + wn * 64 + ni * 16 + lm] = acc[mi][ni][r] + bv4[ni];
            }
        }
    } else {
        __bf16* Vt = (__bf16*)Cout;
#pragma unroll
        for (int ni = 0; ni < 4; ++ni) {
            const int col = bn + wn * 64 + ni * 16 + lm;
            const float bb = bias[col];
            const int hh = col >> 6, dd = col & 63;
#pragma unroll
            for (int mi = 0; mi < 4; ++mi) {
                const int tok = bm + wm * 64 + mi * 16 + g * 4;
                const int b = tok >> 11, s0 = tok & 2047;
                bf16x4 pk;
#pragma unroll
                for (int r = 0; r < 4; ++r) pk[r] = (__bf16)(acc[mi][ni][r] + bb);
                *(bf16x4*)(Vt + ((size_t)(b * kH + hh) * kD + dd) * kS + s0) = pk;
            }
        }
    }
}

// ---------------------------------------------------------------------------
// MFMA flash attention, 32x32x16. BQ=128, 4 waves (32 q each), BK=64.
// K hi/lo + Vt in LDS double-buffered, ONE barrier/tile.
// P partner exchange via __shfl_xor(32). lsum via ones-row MFMA (lacc).
// XCD-chunked block swizzle: 16 q-blocks of one (b,h) share an XCD's L2.
// ---------------------------------------------------------------------------
__global__ __launch_bounds__(256, 2) void flash_attn_mfma(
    const __bf16* __restrict__ Qh, const __bf16* __restrict__ Ql,
    const __bf16* __restrict__ xh, const __bf16* __restrict__ xl,
    const __bf16* __restrict__ VtG, __bf16* __restrict__ AO)
{
    __shared__ __bf16 Kh[2][64 * 64];
    __shared__ __bf16 Kl[2][64 * 64];
    __shared__ __bf16 Vts[2][64 * 64];

    const int tid = threadIdx.x;
    const int l = tid & 63;
    const int w = tid >> 6;
    const int hi = l >> 5;       // lane half (k-block of A/B frags)
    const int lq = l & 31;       // this lane's q column / tile row

    // XCD-chunked remap: 512 blocks, 8 XCDs, 64 works/XCD; the 16 q-tiles of
    // each (b,h) land on one XCD (4 groups x 768KB = 3MB < 4MB L2/XCD).
    const int s = blockIdx.x + 16 * blockIdx.y + 256 * blockIdx.z;
    const int wk = (s & 7) * 64 + (s >> 3);
    const int q0 = (wk & 15) * 128;
    const int h = (wk >> 4) & 15;
    const int b = wk >> 8;

    // Q B-frags: q = q0+32w+lq, d = 16*ks + 8*hi + j
    bf16x8 qh[4], ql[4];
    {
        const size_t qoff = ((size_t)(b * kS + q0 + 32 * w + lq)) * kE + h * kD + 8 * hi;
#pragma unroll
        for (int ks = 0; ks < 4; ++ks) {
            qh[ks] = *(const bf16x8*)(Qh + qoff + 16 * ks);
            ql[ks] = *(const bf16x8*)(Ql + qoff + 16 * ks);
        }
    }
    bf16x8 ones;
#pragma unroll
    for (int j = 0; j < 8; ++j) ones[j] = (__bf16)1.0f;

    f32x16 oacc[2], lacc;
#pragma unroll
    for (int r = 0; r < 16; ++r) { oacc[0][r] = 0.f; oacc[1][r] = 0.f; lacc[r] = 0.f; }
    float mrun = -INFINITY;

    const int srow = 8 * w + (l >> 3);
    const int cpos = l & 7;
    const size_t vthead = ((size_t)(b * kH + h) * kD) * kS;
    const size_t xbase = (size_t)(b * kS) * kE + h * kD;

    auto stage = [&](int buf, int k0) {
#pragma unroll
        for (int j = 0; j < 2; ++j) {
            const int r = 32 * j + srow;
            const int c = cpos ^ (r & 7);
            gload_lds16(xh + xbase + (size_t)(k0 + r) * kE + c * 8, &Kh[buf][j * 2048 + w * 512]);
            gload_lds16(xl + xbase + (size_t)(k0 + r) * kE + c * 8, &Kl[buf][j * 2048 + w * 512]);
            gload_lds16(VtG + vthead + (size_t)r * kS + k0 + c * 8, &Vts[buf][j * 2048 + w * 512]);
        }
    };

    stage(0, 0);
    int cur = 0;
    for (int k0 = 0; k0 < kS; k0 += 64) {
        __syncthreads();                      // buf[cur] staged; buf[cur^1] free
        if (k0 + 64 < kS) stage(cur ^ 1, k0 + 64);

        // ---- QK^T: S^T[key][q], 2 key-tiles of 32, 4 d-steps of 16, 3 passes ----
        f32x16 sacc[2];
#pragma unroll
        for (int r = 0; r < 16; ++r) { sacc[0][r] = 0.f; sacc[1][r] = 0.f; }
#pragma unroll
        for (int kt = 0; kt < 2; ++kt) {
            const int key = 32 * kt + lq;
            const int kr = key * 64;
            const int ksw = key & 7;
#pragma unroll
            for (int ks = 0; ks < 4; ++ks) {
                const int cd = 2 * ks + hi;
                bf16x8 khf = *(const bf16x8*)&Kh[cur][kr + ((cd ^ ksw) * 8)];
                bf16x8 klf = *(const bf16x8*)&Kl[cur][kr + ((cd ^ ksw) * 8)];
                sacc[kt] = __builtin_amdgcn_mfma_f32_32x32x16_bf16(khf, qh[ks], sacc[kt], 0, 0, 0);
                sacc[kt] = __builtin_amdgcn_mfma_f32_32x32x16_bf16(khf, ql[ks], sacc[kt], 0, 0, 0);
                sacc[kt] = __builtin_amdgcn_mfma_f32_32x32x16_bf16(klf, qh[ks], sacc[kt], 0, 0, 0);
            }
        }

        // ---- defer-max online softmax (log2 space); tree max + shfl ----
        float t16[16];
#pragma unroll
        for (int r = 0; r < 16; ++r) t16[r] = fmaxf(sacc[0][r], sacc[1][r]);
#pragma unroll
        for (int st = 8; st > 0; st >>= 1)
#pragma unroll
            for (int r = 0; r < st; ++r) t16[r] = fmaxf(t16[r], t16[r + st]);
        float tmax = fmaxf(t16[0], __shfl_xor(t16[0], 32));
        if (__any(tmax > mrun + 16.0f)) {
            const float mnew = fmaxf(mrun, tmax);
            const float alpha = exp2f(mrun - mnew);
#pragma unroll
            for (int r = 0; r < 16; ++r) {
                oacc[0][r] *= alpha; oacc[1][r] *= alpha; lacc[r] *= alpha;
            }
            mrun = mnew;
        }

        // ---- P in registers + PV (+ lsum rows via ones-MFMA) ----
        // reg r of sacc[kt] holds key_local = (r&3) + 8*(r>>2) + 4*hi (+32*kt).
#pragma unroll
        for (int kt = 0; kt < 2; ++kt) {
            unsigned wds[8], pw[8];
#pragma unroll
            for (int i = 0; i < 8; ++i) {
                const float p0 = exp2f(sacc[kt][2 * i] - mrun);
                const float p1 = exp2f(sacc[kt][2 * i + 1] - mrun);
                wds[i] = pack_bf16(p0, p1);
            }
#pragma unroll
            for (int i = 0; i < 8; ++i) pw[i] = __shfl_xor(wds[i], 32);
            // B-frag (16 keys x 32 q) for k-steps 2kt and 2kt+1:
            u32x4 f0 = hi ? (u32x4){pw[2], pw[3], wds[2], wds[3]}
                          : (u32x4){wds[0], wds[1], pw[0], pw[1]};
            u32x4 f1 = hi ? (u32x4){pw[6], pw[7], wds[6], wds[7]}
                          : (u32x4){wds[4], wds[5], pw[4], pw[5]};
            bf16x8 pf0 = __builtin_bit_cast(bf16x8, f0);
            bf16x8 pf1 = __builtin_bit_cast(bf16x8, f1);
            lacc = __builtin_amdgcn_mfma_f32_32x32x16_bf16(ones, pf0, lacc, 0, 0, 0);
            lacc = __builtin_amdgcn_mfma_f32_32x32x16_bf16(ones, pf1, lacc, 0, 0, 0);
#pragma unroll
            for (int dt = 0; dt < 2; ++dt) {
                const int d = 32 * dt + lq;
                const int dr = d * 64;
                const int dsw = d & 7;
                bf16x8 v0 = *(const bf16x8*)&Vts[cur][dr + (((4 * kt + hi) ^ dsw) * 8)];
                bf16x8 v1 = *(const bf16x8*)&Vts[cur][dr + (((4 * kt + 2 + hi) ^ dsw) * 8)];
                oacc[dt] = __builtin_amdgcn_mfma_f32_32x32x16_bf16(v0, pf0, oacc[dt], 0, 0, 0);
                oacc[dt] = __builtin_amdgcn_mfma_f32_32x32x16_bf16(v1, pf1, oacc[dt], 0, 0, 0);
            }
        }
        cur ^= 1;
    }

    // lacc[0] = full column sum of P for this lane's q (MFMA summed all keys).
    const float inv = 1.0f / lacc[0];
    const size_t obase = ((size_t)(b * kS + q0 + 32 * w + lq)) * kE + h * kD;
#pragma unroll
    for (int dt = 0; dt < 2; ++dt)
#pragma unroll
        for (int rr = 0; rr < 4; ++rr) {
            const int d0 = 32 * dt + 8 * rr + 4 * hi;
            bf16x4 pk;
#pragma unroll
            for (int j = 0; j < 4; ++j) pk[j] = (__bf16)(oacc[dt][4 * rr + j] * inv);
            *(bf16x4*)(AO + obase + d0) = pk;
        }
}

// ---------------------------------------------------------------------------
extern "C" void kernel_launch(void* const* d_in, const int* in_sizes, int n_in,
                              void* d_out, int out_size, void* d_ws, size_t ws_size,
                              hipStream_t stream) {
    (void)in_sizes; (void)n_in; (void)out_size; (void)ws_size;
    const float* x      = (const float*)d_in[0];
    const float* params = (const float*)d_in[1];
    const float* Wv     = (const float*)d_in[2];
    const float* bv     = (const float*)d_in[3];
    const float* Wo     = (const float*)d_in[4];
    const float* bo     = (const float*)d_in[5];
    float* out = (float*)d_out;

    const size_t NE = (size_t)kB * kS * kE;   // 4194304
    const size_t NW = (size_t)kE * kE;        // 1048576

    char* ws = (char*)d_ws;
    size_t off = 0;
    float*  wqk = (float*)(ws + off);  off += (size_t)kH * kD * kD * 4;
    __bf16* xh  = (__bf16*)(ws + off); off += NE * 2;
    __bf16* xl  = (__bf16*)(ws + off); off += NE * 2;
    __bf16* wvb = (__bf16*)(ws + off); off += NW * 2;
    __bf16* wob = (__bf16*)(ws + off); off += NW * 2;
    __bf16* Qh  = (__bf16*)(ws + off); off += NE * 2;
    __bf16* Ql  = (__bf16*)(ws + off); off += NE * 2;
    __bf16* VtG = (__bf16*)(ws + off); off += NE * 2;
    __bf16* AO  = (__bf16*)(ws + off); off += NE * 2;

    cast_bf16_kernel<<<(int)(NW / 4 / 256), 256, 0, stream>>>(Wv, wvb, (int)(NW / 4));
    cast_bf16_kernel<<<(int)(NW / 4 / 256), 256, 0, stream>>>(Wo, wob, (int)(NW / 4));
    build_wqk<<<kH, 256, 0, stream>>>(params, wqk);
    q_proj<<<kB * kS, 256, 0, stream>>>(x, wqk, Qh, Ql, xh, xl);
    gemm_bf16<1><<<dim3(kE / 128, (kB * kS) / 128), 256, 0, stream>>>(
        xh, wvb, bv, (void*)VtG, kB * kS, kE, kE);
    flash_attn_mfma<<<dim3(kS / 128, kH, kB), 256, 0, stream>>>(Qh, Ql, xh, xl, VtG, AO);
    gemm_bf16<0><<<dim3(kE / 128, (kB * kS) / 128), 256, 0, stream>>>(
        AO, wob, bo, (void*)out, kB * kS, kE, kE);
}

// Round 9
// 189.804 us; speedup vs baseline: 1.2683x; 1.0271x over previous
//
#include <hip/hip_runtime.h>
#include <math.h>

// Problem constants
static constexpr int kB = 2;
static constexpr int kS = 2048;
static constexpr int kE = 1024;
static constexpr int kH = 16;
static constexpr int kD = 64;
static constexpr int kTRIL = 2080; // 64*65/2

typedef __attribute__((ext_vector_type(8))) __bf16 bf16x8;
typedef __attribute__((ext_vector_type(4))) __bf16 bf16x4;
typedef __attribute__((ext_vector_type(4))) float f32x4;
typedef __attribute__((ext_vector_type(16))) float f32x16;
typedef __attribute__((ext_vector_type(4))) unsigned int u32x4;

// Split f32 into bf16 hi (truncation) + bf16 lo (RNE of residual).
__device__ __forceinline__ void split_bf16(float f, __bf16& hi, __bf16& lo) {
    unsigned bits = __builtin_bit_cast(unsigned, f);
    hi = __builtin_bit_cast(__bf16, (unsigned short)(bits >> 16));
    float hf = __builtin_bit_cast(float, bits & 0xFFFF0000u);
    lo = (__bf16)(f - hf);
}

// Async global->LDS 16B copy. LDS dest is wave-uniform (HW adds lane*16).
__device__ __forceinline__ void gload_lds16(const void* g, void* l) {
    __builtin_amdgcn_global_load_lds(
        (const __attribute__((address_space(1))) unsigned int*)g,
        (__attribute__((address_space(3))) unsigned int*)l, 16, 0, 0);
}

__device__ __forceinline__ unsigned pack_bf16(float a, float b) {
    unsigned ha = (unsigned)__builtin_bit_cast(unsigned short, (__bf16)a);
    unsigned hb = (unsigned)__builtin_bit_cast(unsigned short, (__bf16)b);
    return ha | (hb << 16);
}

// ---------------------------------------------------------------------------
// Fused setup: blocks [0,1024) cast Wv -> bf16; [1024,2048) cast Wo;
// [2048,2064) build Wqk[h] = L_h @ L_h^T from packed tril params.
// ---------------------------------------------------------------------------
__global__ __launch_bounds__(256) void setup_kernel(
    const float* __restrict__ Wv, const float* __restrict__ Wo,
    const float* __restrict__ params,
    __bf16* __restrict__ wvb, __bf16* __restrict__ wob,
    float* __restrict__ wqk)
{
    const int bid = blockIdx.x;
    if (bid < 2048) {
        const int half = bid >> 10;                 // 0: Wv, 1: Wo
        const int i = (bid & 1023) * 256 + threadIdx.x;
        const float* src = half ? Wo : Wv;
        __bf16* dst = half ? wob : wvb;
        const float4 v = ((const float4*)src)[i];
        bf16x4 o = {(__bf16)v.x, (__bf16)v.y, (__bf16)v.z, (__bf16)v.w};
        ((bf16x4*)dst)[i] = o;
        return;
    }
    // build_wqk for head h
    __shared__ float p[kTRIL];
    const int h = bid - 2048;
    for (int i = threadIdx.x; i < kTRIL; i += 256) p[i] = params[h * kTRIL + i];
    __syncthreads();
    for (int idx = threadIdx.x; idx < kD * kD; idx += 256) {
        const int i = idx >> 6;
        const int j = idx & 63;
        const int m = i < j ? i : j;
        const float* pi = p + (i * (i + 1)) / 2;
        const float* pj = p + (j * (j + 1)) / 2;
        float s = 0.f;
        for (int k = 0; k <= m; ++k) s += pi[k] * pj[k];
        wqk[h * kD * kD + idx] = s;
    }
}

// ---------------------------------------------------------------------------
// Q = (xh @ Wqk) * 0.125 * log2(e), written as split bf16 (Qh, Ql).
// Also emits the hi/lo split of x itself (fused).
// ---------------------------------------------------------------------------
__global__ __launch_bounds__(256) void q_proj(
    const float* __restrict__ x, const float* __restrict__ wqk,
    __bf16* __restrict__ Qh, __bf16* __restrict__ Ql,
    __bf16* __restrict__ xhO, __bf16* __restrict__ xlO)
{
    __shared__ float xs[kE];
    const int bs = blockIdx.x;
    const int tid = threadIdx.x;
    const float4 xv4 = ((const float4*)(x + (size_t)bs * kE))[tid];
    ((float4*)xs)[tid] = xv4;
    {
        const float f[4] = {xv4.x, xv4.y, xv4.z, xv4.w};
        bf16x4 hv, lv;
#pragma unroll
        for (int j = 0; j < 4; ++j) { __bf16 a, c; split_bf16(f[j], a, c); hv[j] = a; lv[j] = c; }
        ((bf16x4*)(xhO + (size_t)bs * kE))[tid] = hv;
        ((bf16x4*)(xlO + (size_t)bs * kE))[tid] = lv;
    }
    __syncthreads();
    const int o = tid * 4;
    const int h = o >> 6;
    const int e = o & 63;
    const float* W = wqk + h * kD * kD;
    float a0 = 0.f, a1 = 0.f, a2 = 0.f, a3 = 0.f;
    const float* xh = xs + h * kD;
#pragma unroll 8
    for (int d = 0; d < kD; ++d) {
        const float xv = xh[d];
        const float4 w = *(const float4*)(W + d * kD + e);
        a0 += xv * w.x; a1 += xv * w.y; a2 += xv * w.z; a3 += xv * w.w;
    }
    const float sc = 0.125f * 1.44269504088896340736f;
    const float f[4] = {a0 * sc, a1 * sc, a2 * sc, a3 * sc};
    bf16x4 hv, lv;
#pragma unroll
    for (int j = 0; j < 4; ++j) { __bf16 a, b; split_bf16(f[j], a, b); hv[j] = a; lv[j] = b; }
    ((bf16x4*)(Qh + (size_t)bs * kE))[tid] = hv;
    ((bf16x4*)(Ql + (size_t)bs * kE))[tid] = lv;
}

// ---------------------------------------------------------------------------
// Single-pass bf16 MFMA GEMM: C = A @ Bw^T + bias (f32 accumulate).
// 128x128 tile, BK=64, 4 waves (2x2), 2-phase double-buffered global_load_lds.
// MODE 0: C f32 [M,N].  MODE 1: C bf16 transposed to Vt[b,h,d,s].
// ---------------------------------------------------------------------------
template <int MODE>
__global__ __launch_bounds__(256) void gemm_bf16(
    const __bf16* __restrict__ A, const __bf16* __restrict__ Bw,
    const float* __restrict__ bias, void* __restrict__ Cout,
    int M, int N, int K)
{
    __shared__ __bf16 Ab[2][128 * 64];
    __shared__ __bf16 Bb[2][128 * 64];

    const int tid = threadIdx.x;
    const int w = tid >> 6, l = tid & 63;
    const int g = l >> 4, lm = l & 15;
    const int wm = w >> 1, wn = w & 1;
    const int bm = blockIdx.y * 128, bn = blockIdx.x * 128;
    const int srow = 8 * w + (l >> 3);
    const int cp = l & 7;

    f32x4 acc[4][4];
#pragma unroll
    for (int i = 0; i < 4; ++i)
#pragma unroll
        for (int j = 0; j < 4; ++j) acc[i][j] = (f32x4){0.f, 0.f, 0.f, 0.f};

    auto stage = [&](int buf, int k0) {
#pragma unroll
        for (int j = 0; j < 4; ++j) {
            const int r = 32 * j + srow;
            const int c = cp ^ (r & 7);
            gload_lds16(A + (size_t)(bm + r) * K + k0 + c * 8, &Ab[buf][j * 2048 + w * 512]);
            gload_lds16(Bw + (size_t)(bn + r) * K + k0 + c * 8, &Bb[buf][j * 2048 + w * 512]);
        }
    };

    stage(0, 0);
    __syncthreads();
    int cur = 0;
    const int NT = K / 64;
    for (int t = 0; t < NT; ++t) {
        if (t + 1 < NT) stage(cur ^ 1, 64 * (t + 1));

        bf16x8 a[4][2], bf[4][2];
#pragma unroll
        for (int i = 0; i < 4; ++i) {
            const int rA = wm * 64 + i * 16 + lm;
            const int rB = wn * 64 + i * 16 + lm;
#pragma unroll
            for (int ks = 0; ks < 2; ++ks) {
                a[i][ks]  = *(const bf16x8*)&Ab[cur][rA * 64 + (((4 * ks + g) ^ (rA & 7)) * 8)];
                bf[i][ks] = *(const bf16x8*)&Bb[cur][rB * 64 + (((4 * ks + g) ^ (rB & 7)) * 8)];
            }
        }
        __builtin_amdgcn_s_setprio(1);
#pragma unroll
        for (int ks = 0; ks < 2; ++ks)
#pragma unroll
            for (int mi = 0; mi < 4; ++mi)
#pragma unroll
                for (int ni = 0; ni < 4; ++ni)
                    acc[mi][ni] = __builtin_amdgcn_mfma_f32_16x16x32_bf16(
                        a[mi][ks], bf[ni][ks], acc[mi][ni], 0, 0, 0);
        __builtin_amdgcn_s_setprio(0);

        __syncthreads();
        cur ^= 1;
    }

    if (MODE == 0) {
        float bv4[4];
#pragma unroll
        for (int ni = 0; ni < 4; ++ni) bv4[ni] = bias[bn + wn * 64 + ni * 16 + lm];
        float* C = (float*)Cout;
#pragma unroll
        for (int mi = 0; mi < 4; ++mi) {
            const int row0 = bm + wm * 64 + mi * 16 + g * 4;
#pragma unroll
            for (int r = 0; r < 4; ++r) {
                float* crow = C + (size_t)(row0 + r) * N;
#pragma unroll
                for (int ni = 0; ni < 4; ++ni)
                    crow[bn + wn * 64 + ni * 16 + lm] = acc[mi][ni][r] + bv4[ni];
            }
        }
    } else {
        __bf16* Vt = (__bf16*)Cout;
#pragma unroll
        for (int ni = 0; ni < 4; ++ni) {
            const int col = bn + wn * 64 + ni * 16 + lm;
            const float bb = bias[col];
            const int hh = col >> 6, dd = col & 63;
#pragma unroll
            for (int mi = 0; mi < 4; ++mi) {
                const int tok = bm + wm * 64 + mi * 16 + g * 4;
                const int b = tok >> 11, s0 = tok & 2047;
                bf16x4 pk;
#pragma unroll
                for (int r = 0; r < 4; ++r) pk[r] = (__bf16)(acc[mi][ni][r] + bb);
                *(bf16x4*)(Vt + ((size_t)(b * kH + hh) * kD + dd) * kS + s0) = pk;
            }
        }
    }
}

// ---------------------------------------------------------------------------
// MFMA flash attention, 32x32x16. BQ=128, 4 waves (32 q each), BK=64.
// K hi/lo + Vt in LDS double-buffered, ONE barrier/tile.
// P partner exchange via __shfl_xor(32). lsum via ones-row MFMA (lacc).
// XCD-chunked block swizzle; setprio(1) around MFMA clusters (T5).
// ---------------------------------------------------------------------------
__global__ __launch_bounds__(256, 2) void flash_attn_mfma(
    const __bf16* __restrict__ Qh, const __bf16* __restrict__ Ql,
    const __bf16* __restrict__ xh, const __bf16* __restrict__ xl,
    const __bf16* __restrict__ VtG, __bf16* __restrict__ AO)
{
    __shared__ __bf16 Kh[2][64 * 64];
    __shared__ __bf16 Kl[2][64 * 64];
    __shared__ __bf16 Vts[2][64 * 64];

    const int tid = threadIdx.x;
    const int l = tid & 63;
    const int w = tid >> 6;
    const int hi = l >> 5;       // lane half (k-block of A/B frags)
    const int lq = l & 31;       // this lane's q column / tile row

    // XCD-chunked remap: 512 blocks, 8 XCDs, 64 works/XCD; the 16 q-tiles of
    // each (b,h) land on one XCD (4 groups x 768KB = 3MB < 4MB L2/XCD).
    const int s = blockIdx.x + 16 * blockIdx.y + 256 * blockIdx.z;
    const int wk = (s & 7) * 64 + (s >> 3);
    const int q0 = (wk & 15) * 128;
    const int h = (wk >> 4) & 15;
    const int b = wk >> 8;

    // Q B-frags: q = q0+32w+lq, d = 16*ks + 8*hi + j
    bf16x8 qh[4], ql[4];
    {
        const size_t qoff = ((size_t)(b * kS + q0 + 32 * w + lq)) * kE + h * kD + 8 * hi;
#pragma unroll
        for (int ks = 0; ks < 4; ++ks) {
            qh[ks] = *(const bf16x8*)(Qh + qoff + 16 * ks);
            ql[ks] = *(const bf16x8*)(Ql + qoff + 16 * ks);
        }
    }
    bf16x8 ones;
#pragma unroll
    for (int j = 0; j < 8; ++j) ones[j] = (__bf16)1.0f;

    f32x16 oacc[2], lacc;
#pragma unroll
    for (int r = 0; r < 16; ++r) { oacc[0][r] = 0.f; oacc[1][r] = 0.f; lacc[r] = 0.f; }
    float mrun = -INFINITY;

    const int srow = 8 * w + (l >> 3);
    const int cpos = l & 7;
    const size_t vthead = ((size_t)(b * kH + h) * kD) * kS;
    const size_t xbase = (size_t)(b * kS) * kE + h * kD;

    auto stage = [&](int buf, int k0) {
#pragma unroll
        for (int j = 0; j < 2; ++j) {
            const int r = 32 * j + srow;
            const int c = cpos ^ (r & 7);
            gload_lds16(xh + xbase + (size_t)(k0 + r) * kE + c * 8, &Kh[buf][j * 2048 + w * 512]);
            gload_lds16(xl + xbase + (size_t)(k0 + r) * kE + c * 8, &Kl[buf][j * 2048 + w * 512]);
            gload_lds16(VtG + vthead + (size_t)r * kS + k0 + c * 8, &Vts[buf][j * 2048 + w * 512]);
        }
    };

    stage(0, 0);
    int cur = 0;
    for (int k0 = 0; k0 < kS; k0 += 64) {
        __syncthreads();                      // buf[cur] staged; buf[cur^1] free
        if (k0 + 64 < kS) stage(cur ^ 1, k0 + 64);

        // ---- QK^T: S^T[key][q], 2 key-tiles of 32, 4 d-steps of 16, 3 passes ----
        f32x16 sacc[2];
#pragma unroll
        for (int r = 0; r < 16; ++r) { sacc[0][r] = 0.f; sacc[1][r] = 0.f; }
#pragma unroll
        for (int kt = 0; kt < 2; ++kt) {
            const int key = 32 * kt + lq;
            const int kr = key * 64;
            const int ksw = key & 7;
            __builtin_amdgcn_s_setprio(1);
#pragma unroll
            for (int ks = 0; ks < 4; ++ks) {
                const int cd = 2 * ks + hi;
                bf16x8 khf = *(const bf16x8*)&Kh[cur][kr + ((cd ^ ksw) * 8)];
                bf16x8 klf = *(const bf16x8*)&Kl[cur][kr + ((cd ^ ksw) * 8)];
                sacc[kt] = __builtin_amdgcn_mfma_f32_32x32x16_bf16(khf, qh[ks], sacc[kt], 0, 0, 0);
                sacc[kt] = __builtin_amdgcn_mfma_f32_32x32x16_bf16(khf, ql[ks], sacc[kt], 0, 0, 0);
                sacc[kt] = __builtin_amdgcn_mfma_f32_32x32x16_bf16(klf, qh[ks], sacc[kt], 0, 0, 0);
            }
            __builtin_amdgcn_s_setprio(0);
        }

        // ---- defer-max online softmax (log2 space); tree max + shfl ----
        float t16[16];
#pragma unroll
        for (int r = 0; r < 16; ++r) t16[r] = fmaxf(sacc[0][r], sacc[1][r]);
#pragma unroll
        for (int st = 8; st > 0; st >>= 1)
#pragma unroll
            for (int r = 0; r < st; ++r) t16[r] = fmaxf(t16[r], t16[r + st]);
        float tmax = fmaxf(t16[0], __shfl_xor(t16[0], 32));
        if (__any(tmax > mrun + 16.0f)) {
            const float mnew = fmaxf(mrun, tmax);
            const float alpha = exp2f(mrun - mnew);
#pragma unroll
            for (int r = 0; r < 16; ++r) {
                oacc[0][r] *= alpha; oacc[1][r] *= alpha; lacc[r] *= alpha;
            }
            mrun = mnew;
        }

        // ---- P in registers + PV (+ lsum rows via ones-MFMA) ----
        // reg r of sacc[kt] holds key_local = (r&3) + 8*(r>>2) + 4*hi (+32*kt).
#pragma unroll
        for (int kt = 0; kt < 2; ++kt) {
            unsigned wds[8], pw[8];
#pragma unroll
            for (int i = 0; i < 8; ++i) {
                const float p0 = exp2f(sacc[kt][2 * i] - mrun);
                const float p1 = exp2f(sacc[kt][2 * i + 1] - mrun);
                wds[i] = pack_bf16(p0, p1);
            }
#pragma unroll
            for (int i = 0; i < 8; ++i) pw[i] = __shfl_xor(wds[i], 32);
            // B-frag (16 keys x 32 q) for k-steps 2kt and 2kt+1:
            u32x4 f0 = hi ? (u32x4){pw[2], pw[3], wds[2], wds[3]}
                          : (u32x4){wds[0], wds[1], pw[0], pw[1]};
            u32x4 f1 = hi ? (u32x4){pw[6], pw[7], wds[6], wds[7]}
                          : (u32x4){wds[4], wds[5], pw[4], pw[5]};
            bf16x8 pf0 = __builtin_bit_cast(bf16x8, f0);
            bf16x8 pf1 = __builtin_bit_cast(bf16x8, f1);
            __builtin_amdgcn_s_setprio(1);
            lacc = __builtin_amdgcn_mfma_f32_32x32x16_bf16(ones, pf0, lacc, 0, 0, 0);
            lacc = __builtin_amdgcn_mfma_f32_32x32x16_bf16(ones, pf1, lacc, 0, 0, 0);
#pragma unroll
            for (int dt = 0; dt < 2; ++dt) {
                const int d = 32 * dt + lq;
                const int dr = d * 64;
                const int dsw = d & 7;
                bf16x8 v0 = *(const bf16x8*)&Vts[cur][dr + (((4 * kt + hi) ^ dsw) * 8)];
                bf16x8 v1 = *(const bf16x8*)&Vts[cur][dr + (((4 * kt + 2 + hi) ^ dsw) * 8)];
                oacc[dt] = __builtin_amdgcn_mfma_f32_32x32x16_bf16(v0, pf0, oacc[dt], 0, 0, 0);
                oacc[dt] = __builtin_amdgcn_mfma_f32_32x32x16_bf16(v1, pf1, oacc[dt], 0, 0, 0);
            }
            __builtin_amdgcn_s_setprio(0);
        }
        cur ^= 1;
    }

    // lacc[0] = full column sum of P for this lane's q (MFMA summed all keys).
    const float inv = 1.0f / lacc[0];
    const size_t obase = ((size_t)(b * kS + q0 + 32 * w + lq)) * kE + h * kD;
#pragma unroll
    for (int dt = 0; dt < 2; ++dt)
#pragma unroll
        for (int rr = 0; rr < 4; ++rr) {
            const int d0 = 32 * dt + 8 * rr + 4 * hi;
            bf16x4 pk;
#pragma unroll
            for (int j = 0; j < 4; ++j) pk[j] = (__bf16)(oacc[dt][4 * rr + j] * inv);
            *(bf16x4*)(AO + obase + d0) = pk;
        }
}

// ---------------------------------------------------------------------------
extern "C" void kernel_launch(void* const* d_in, const int* in_sizes, int n_in,
                              void* d_out, int out_size, void* d_ws, size_t ws_size,
                              hipStream_t stream) {
    (void)in_sizes; (void)n_in; (void)out_size; (void)ws_size;
    const float* x      = (const float*)d_in[0];
    const float* params = (const float*)d_in[1];
    const float* Wv     = (const float*)d_in[2];
    const float* bv     = (const float*)d_in[3];
    const float* Wo     = (const float*)d_in[4];
    const float* bo     = (const float*)d_in[5];
    float* out = (float*)d_out;

    const size_t NE = (size_t)kB * kS * kE;   // 4194304
    const size_t NW = (size_t)kE * kE;        // 1048576

    char* ws = (char*)d_ws;
    size_t off = 0;
    float*  wqk = (float*)(ws + off);  off += (size_t)kH * kD * kD * 4;
    __bf16* xh  = (__bf16*)(ws + off); off += NE * 2;
    __bf16* xl  = (__bf16*)(ws + off); off += NE * 2;
    __bf16* wvb = (__bf16*)(ws + off); off += NW * 2;
    __bf16* wob = (__bf16*)(ws + off); off += NW * 2;
    __bf16* Qh  = (__bf16*)(ws + off); off += NE * 2;
    __bf16* Ql  = (__bf16*)(ws + off); off += NE * 2;
    __bf16* VtG = (__bf16*)(ws + off); off += NE * 2;
    __bf16* AO  = (__bf16*)(ws + off); off += NE * 2;

    setup_kernel<<<2064, 256, 0, stream>>>(Wv, Wo, params, wvb, wob, wqk);
    q_proj<<<kB * kS, 256, 0, stream>>>(x, wqk, Qh, Ql, xh, xl);
    gemm_bf16<1><<<dim3(kE / 128, (kB * kS) / 128), 256, 0, stream>>>(
        xh, wvb, bv, (void*)VtG, kB * kS, kE, kE);
    flash_attn_mfma<<<dim3(kS / 128, kH, kB), 256, 0, stream>>>(Qh, Ql, xh, xl, VtG, AO);
    gemm_bf16<0><<<dim3(kE / 128, (kB * kS) / 128), 256, 0, stream>>>(
        AO, wob, bo, (void*)out, kB * kS, kE, kE);
}